// Round 1
// baseline (533.910 us; speedup 1.0000x reference)
//
#include <hip/hip_runtime.h>
#include <math.h>

#define BATCH 65536
#define NODES 1024
#define ZD    256

// Output layout (flat float32, reference return order):
// z_e [65536*256], k [65536], z_q [65536*256], nw [65536*1024], dist [65536*1024]
#define OFF_ZE   0ull
#define OFF_K    16777216ull
#define OFF_ZQ   16842752ull
#define OFF_NW   33619968ull
#define OFF_DIST 100728832ull

// ---------------- row norms: one wave (64 lanes) per row of 256 floats ----------------
__global__ __launch_bounds__(256) void row_norms_k(const float* __restrict__ X,
                                                   float* __restrict__ out, int nrows) {
    int w    = blockIdx.x * 4 + (threadIdx.x >> 6);
    int lane = threadIdx.x & 63;
    if (w >= nrows) return;
    const float4* xp = (const float4*)(X + (size_t)w * ZD);
    float4 v = xp[lane];                       // 64 lanes * 4 = 256 exactly
    float s = v.x * v.x + v.y * v.y + v.z * v.z + v.w * v.w;
#pragma unroll
    for (int off = 32; off; off >>= 1) s += __shfl_down(s, off);
    if (lane == 0) out[w] = s;
}

// ---------------- distance GEMM: D = max(xn + yn - 2*A.B^T, 0) ----------------
// BM=128, BN=128, BK=32, 256 threads, 8x8 micro-tile (split 4+4 at +64).
__global__ __launch_bounds__(256) void dist_gemm_k(const float* __restrict__ A,
                                                   const float* __restrict__ B,
                                                   const float* __restrict__ xn,
                                                   const float* __restrict__ yn,
                                                   float* __restrict__ D) {
    __shared__ float As[32][132];   // [k][m], padded to 132 for write-conflict relief
    __shared__ float Bs[32][132];   // [k][n]

    const int tid = threadIdx.x;
    const int bm  = blockIdx.y;     // 0..511
    const int bn  = blockIdx.x;     // 0..7
    const int tm  = tid & 15;
    const int tn  = tid >> 4;

    const int kq   = tid & 7;       // which float4 along k (k = kq*4)
    const int row0 = tid >> 3;      // 0..31

    const float4* A4 = (const float4*)A;
    const float4* B4 = (const float4*)B;
    const int bmBase = bm * 128;
    const int bnBase = bn * 128;

    float acc[8][8];
#pragma unroll
    for (int i = 0; i < 8; ++i)
#pragma unroll
        for (int j = 0; j < 8; ++j) acc[i][j] = 0.0f;

    for (int kt = 0; kt < 8; ++kt) {
        // stage A,B tiles (transposed to [k][m]) into LDS
#pragma unroll
        for (int i = 0; i < 4; ++i) {
            int row = row0 + 32 * i;
            float4 va = A4[(size_t)(bmBase + row) * 64 + kt * 8 + kq];
            As[kq * 4 + 0][row] = va.x;
            As[kq * 4 + 1][row] = va.y;
            As[kq * 4 + 2][row] = va.z;
            As[kq * 4 + 3][row] = va.w;
            float4 vb = B4[(size_t)(bnBase + row) * 64 + kt * 8 + kq];
            Bs[kq * 4 + 0][row] = vb.x;
            Bs[kq * 4 + 1][row] = vb.y;
            Bs[kq * 4 + 2][row] = vb.z;
            Bs[kq * 4 + 3][row] = vb.w;
        }
        __syncthreads();

#pragma unroll
        for (int kk = 0; kk < 32; ++kk) {
            float4 a0 = *(const float4*)&As[kk][tm * 4];
            float4 a1 = *(const float4*)&As[kk][tm * 4 + 64];
            float4 b0 = *(const float4*)&Bs[kk][tn * 4];
            float4 b1 = *(const float4*)&Bs[kk][tn * 4 + 64];
            float av[8] = {a0.x, a0.y, a0.z, a0.w, a1.x, a1.y, a1.z, a1.w};
            float bv[8] = {b0.x, b0.y, b0.z, b0.w, b1.x, b1.y, b1.z, b1.w};
#pragma unroll
            for (int i = 0; i < 8; ++i)
#pragma unroll
                for (int j = 0; j < 8; ++j) acc[i][j] = fmaf(av[i], bv[j], acc[i][j]);
        }
        __syncthreads();
    }

    // epilogue: d = max((xn + yn) - 2*dot, 0)  -- replicate reference rounding order
#pragma unroll
    for (int i = 0; i < 8; ++i) {
        int r = bmBase + tm * 4 + (i & 3) + (i >> 2) * 64;
        float xnv = xn[r];
        float* drow = D + (size_t)r * NODES + bnBase;
#pragma unroll
        for (int jh = 0; jh < 2; ++jh) {
            int c0 = tn * 4 + jh * 64;
            float4 o;
            o.x = fmaxf((xnv + yn[bnBase + c0 + 0]) - 2.0f * acc[i][jh * 4 + 0], 0.0f);
            o.y = fmaxf((xnv + yn[bnBase + c0 + 1]) - 2.0f * acc[i][jh * 4 + 1], 0.0f);
            o.z = fmaxf((xnv + yn[bnBase + c0 + 2]) - 2.0f * acc[i][jh * 4 + 2], 0.0f);
            o.w = fmaxf((xnv + yn[bnBase + c0 + 3]) - 2.0f * acc[i][jh * 4 + 3], 0.0f);
            *(float4*)(drow + c0) = o;
        }
    }
}

// ---------------- finish: argmin + k + z_q gather + z_e copy + neighbour weights ----------------
__global__ __launch_bounds__(256) void finish_k(const float* __restrict__ ze,
                                                const float* __restrict__ cb,
                                                const int* __restrict__ epoch_p,
                                                const float* __restrict__ dist,
                                                float* __restrict__ out_ze,
                                                float* __restrict__ out_k,
                                                float* __restrict__ out_zq,
                                                float* __restrict__ out_nw) {
    int row  = blockIdx.x * 4 + (threadIdx.x >> 6);
    int lane = threadIdx.x & 63;

    // sigma from epoch (match SIGMAS: 16*exp(-ep*ln(32)/100), f64)
    int ep = epoch_p[0];
    double sig = 16.0 * exp((double)ep * -0.034657359027997265);
    float denomF = (float)(2.0 * sig * sig);
    float ninv = -1.0f / denomF;

    // argmin over the dist row (tie -> lowest index, numpy semantics)
    const float4* dp = (const float4*)(dist + (size_t)row * NODES);
    float bv = INFINITY;
    int bi = 0;
#pragma unroll
    for (int i = 0; i < 4; ++i) {
        int q = i * 64 + lane;
        float4 v = dp[q];
        int n = q * 4;
        if (v.x < bv) { bv = v.x; bi = n; }
        if (v.y < bv) { bv = v.y; bi = n + 1; }
        if (v.z < bv) { bv = v.z; bi = n + 2; }
        if (v.w < bv) { bv = v.w; bi = n + 3; }
    }
#pragma unroll
    for (int off = 32; off; off >>= 1) {
        float ov = __shfl_down(bv, off);
        int   oi = __shfl_down(bi, off);
        if (ov < bv || (ov == bv && oi < bi)) { bv = ov; bi = oi; }
    }
    int k = __shfl(bi, 0);
    if (lane == 0) out_k[row] = (float)k;

    // z_q gather + z_e passthrough (64 lanes * float4 = 256)
    const float4* cbp = (const float4*)(cb + (size_t)k * ZD);
    const float4* zep = (const float4*)(ze + (size_t)row * ZD);
    ((float4*)(out_zq + (size_t)row * ZD))[lane] = cbp[lane];
    ((float4*)(out_ze + (size_t)row * ZD))[lane] = zep[lane];

    // neighbour weights: w[n] = exp(-((n/32 - k%32)^2 + (n%32 - k/32)^2)/(2 sig^2))
    int kx = k >> 5, ky = k & 31;
    float4* nwp = (float4*)(out_nw + (size_t)row * NODES);
#pragma unroll
    for (int i = 0; i < 4; ++i) {
        int q = i * 64 + lane;
        int n = q * 4;
        float4 w;
        {
            int n0 = n;
            int dx = (n0 >> 5) - ky, dy = (n0 & 31) - kx;
            w.x = __expf((float)(dx * dx + dy * dy) * ninv);
        }
        {
            int n0 = n + 1;
            int dx = (n0 >> 5) - ky, dy = (n0 & 31) - kx;
            w.y = __expf((float)(dx * dx + dy * dy) * ninv);
        }
        {
            int n0 = n + 2;
            int dx = (n0 >> 5) - ky, dy = (n0 & 31) - kx;
            w.z = __expf((float)(dx * dx + dy * dy) * ninv);
        }
        {
            int n0 = n + 3;
            int dx = (n0 >> 5) - ky, dy = (n0 & 31) - kx;
            w.w = __expf((float)(dx * dx + dy * dy) * ninv);
        }
        nwp[q] = w;
    }
}

extern "C" void kernel_launch(void* const* d_in, const int* in_sizes, int n_in,
                              void* d_out, int out_size, void* d_ws, size_t ws_size,
                              hipStream_t stream) {
    const float* z_e      = (const float*)d_in[0];
    const float* codebook = (const float*)d_in[1];
    const int*   epoch_p  = (const int*)d_in[2];
    float* out = (float*)d_out;

    float* xn = (float*)d_ws;            // [65536]
    float* yn = xn + BATCH;              // [1024]

    // 1) row norms
    row_norms_k<<<BATCH / 4, 256, 0, stream>>>(z_e, xn, BATCH);
    row_norms_k<<<NODES / 4, 256, 0, stream>>>(codebook, yn, NODES);

    // 2) distance matrix
    dim3 grid(NODES / 128, BATCH / 128);
    dist_gemm_k<<<grid, 256, 0, stream>>>(z_e, codebook, xn, yn, out + OFF_DIST);

    // 3) argmin + outputs
    finish_k<<<BATCH / 4, 256, 0, stream>>>(z_e, codebook, epoch_p, out + OFF_DIST,
                                            out + OFF_ZE, out + OFF_K, out + OFF_ZQ,
                                            out + OFF_NW);
}